// Round 15
// baseline (83.833 us; speedup 1.0000x reference)
//
#include <hip/hip_runtime.h>
#include <hip/hip_bf16.h>
#include <math.h>

#define BB 2
#define NN 512
#define KK 128
#define EE 768
#define NUM_EDGES 1536
#define RPB 2   // rows per block; grid = B*N/RPB = 512 blocks x 512 threads = 2 blocks/CU

// ---------------- single fused kernel: 2 rows per 512-thread block ----------------
// Same per-group (256-thread) phase code as R14 (proven 59.8 us), but 2 blocks/CU
// so one block's A/B/D bubbles hide under the other block's phase-C store stream.
__global__ __launch_bounds__(512) void edge_fused2r_kernel(
    const float* __restrict__ pos,
    const int* __restrict__ node_type_edge,
    const int* __restrict__ padding_mask,
    const int* __restrict__ mask_aa,
    const int* __restrict__ mask_pos,
    const int* __restrict__ time_pos,
    const float* __restrict__ means,
    const float* __restrict__ stds,
    const float* __restrict__ mul_w,
    const float* __restrict__ bias_w,
    const float* __restrict__ proj_w,   // [K,E]
    const float* __restrict__ proj_b,   // [E]
    const float* __restrict__ t_w1, const float* __restrict__ t_b1,
    const float* __restrict__ t_w2, const float* __restrict__ t_b2,
    float* __restrict__ out_ef,    // [B,N,N,K]
    float* __restrict__ out_merge, // [B,N,E]
    float* __restrict__ out_dp)    // [B,N,N,3]
{
    __shared__ float e2[2][KK];
    __shared__ float h2[2][KK];
    __shared__ float tv[2][KK];            // tv[0]=2*t_enc(t_b), tv[1]=2*t_enc(0)
    __shared__ float xv[RPB][NN];          // per-row mul*dist+bias (4 KB)
    __shared__ unsigned char fl[RPB][NN];  // per-row flags (1 KB)
    __shared__ float red[RPB][4 * KK];     // per-row j-group partials (4 KB)
    __shared__ float sums[RPB][KK];        // per-row k-sums (1 KB)
    __shared__ int padr[RPB];

    const int bi0 = blockIdx.x * RPB;      // 2 rows, same b (bi0 even)
    const int b = bi0 >> 9;
    const int tid = threadIdx.x;
    const int grp = tid >> 8;              // 0..1 : row group
    const int gt  = tid & 255;             // thread-in-group (R4's "tid")
    const int bi  = bi0 + grp;
    const int i   = bi & (NN - 1);

    // ---- phase A (threads 0..255, R14-exact) ----
    if (grp == 0) {
        const int enc = gt >> 7;
        const int k = gt & 127;
        const float t = (enc == 0) ? (float)time_pos[b] : 0.0f;
        const int kk = k & 63;
        const float freq = __expf(-logf(10000.0f) * (float)kk * (1.0f / 64.0f));
        const float arg = t * freq;
        e2[enc][k] = (k < 64) ? cosf(arg) : sinf(arg);
    }
    __syncthreads();
    if (grp == 0) {
        const int enc = gt >> 7;
        const int k = gt & 127;
        float acc = t_b1[k];
#pragma unroll 8
        for (int r = 0; r < KK; ++r) acc += e2[enc][r] * t_w1[r * KK + k];
        h2[enc][k] = acc / (1.0f + __expf(-acc));
    }
    __syncthreads();
    if (grp == 0) {
        const int enc = gt >> 7;
        const int k = gt & 127;
        float acc2 = t_b2[k];
#pragma unroll 8
        for (int r = 0; r < KK; ++r) acc2 += h2[enc][r] * t_w2[r * KK + k];
        tv[enc][k] = 2.0f * acc2;
    }

    // ---- phase B: group g handles row g (R14-exact per-thread work) ----
    const float pix = pos[(b * NN + i) * 3 + 0];
    const float piy = pos[(b * NN + i) * 3 + 1];
    const float piz = pos[(b * NN + i) * 3 + 2];
    const int maa_i  = mask_aa[b * NN + i];
    const int mpos_i = mask_pos[b * NN + i];

    for (int j = gt; j < NN; j += 256) {
        const float dx = pos[(b * NN + j) * 3 + 0] - pix;
        const float dy = pos[(b * NN + j) * 3 + 1] - piy;
        const float dz = pos[(b * NN + j) * 3 + 2] - piz;
        const float dist = sqrtf(dx * dx + dy * dy + dz * dz);
        const float invd = 1.0f / (dist + 1e-5f);
        const size_t dpo = ((size_t)bi * NN + j) * 3;
        out_dp[dpo + 0] = dx * invd;
        out_dp[dpo + 1] = dy * invd;
        out_dp[dpo + 2] = dz * invd;

        const int base = (bi * NN + j) * 2;
        int e0 = node_type_edge[base + 0];
        int e1 = node_type_edge[base + 1];
        if (maa_i)               e0 = 0;
        if (mask_aa[b * NN + j]) e1 = 0;
        const float mul  = mul_w[e0]  + mul_w[e1];
        const float bias = bias_w[e0] + bias_w[e1];
        xv[grp][j] = mul * dist + bias;

        const int md  = (mpos_i | mask_pos[b * NN + j]) ? 1 : 0;
        const int pad = padding_mask[b * NN + j] ? 2 : 0;
        fl[grp][j] = (unsigned char)(md | pad);
    }
    if (gt == 0) padr[grp] = padding_mask[b * NN + i];
    __syncthreads();   // tv/xv/fl visible

    // ---- phase C: group g = row g; R14-exact (2 k/thread, 4 j-groups, float2) ----
    const int k0 = (gt & 63) * 2;
    const int jg = gt >> 6;
    const float a = sqrtf(2.0f * 3.14159f);

    const float mean0 = means[k0];
    const float mean1 = means[k0 + 1];
    const float sd0 = fabsf(stds[k0]) + 0.01f;
    const float sd1 = fabsf(stds[k0 + 1]) + 0.01f;
    const float inv0 = 1.0f / sd0, inv1 = 1.0f / sd1;
    const float coef0 = 1.0f / (a * sd0), coef1 = 1.0f / (a * sd1);
    const float t2_0  = tv[0][k0];
    const float t2_1  = tv[0][k0 + 1];
    const float t02_0 = tv[1][k0];
    const float t02_1 = tv[1][k0 + 1];

    float s0 = 0.0f, s1 = 0.0f;
    const size_t efbase = (size_t)bi * NN * KK;
    const float* __restrict__ xvr = xv[grp];
    const unsigned char* __restrict__ flr = fl[grp];

    for (int jj = 0; jj < NN / 4; ++jj) {
        const int j = jj * 4 + jg;
        const float x = xvr[j];
        const unsigned char f = flr[j];

        const float u0 = (x - mean0) * inv0;
        const float u1 = (x - mean1) * inv1;
        float v0 = __expf(-0.5f * u0 * u0) * coef0 + ((f & 1) ? t2_0 : t02_0);
        float v1 = __expf(-0.5f * u1 * u1) * coef1 + ((f & 1) ? t2_1 : t02_1);
        if (f & 2) { v0 = 0.0f; v1 = 0.0f; }
        s0 += v0; s1 += v1;

        float2 pack; pack.x = v0; pack.y = v1;
        *reinterpret_cast<float2*>(&out_ef[efbase + (size_t)j * KK + k0]) = pack;
    }

    red[grp][jg * KK + k0]     = s0;
    red[grp][jg * KK + k0 + 1] = s1;
    __syncthreads();

    // reduce: threads 0..255 -> (row = tid>>7, k = tid&127)
    if (tid < RPB * KK) {
        const int r = tid >> 7;
        const int k = tid & 127;
        const float* rr = red[r];
        sums[r][k] = rr[k] + rr[KK + k] + rr[2 * KK + k] + rr[3 * KK + k];
    }
    __syncthreads();

    // ---- phase D: ONE proj_w pass for 2 rows ----
    // all 512 threads own e=tid; threads 0..255 also own e=512+tid
    {
        float a00 = 0.f, a01 = 0.f, a10 = 0.f, a11 = 0.f;
        const bool two = (tid < 256);
#pragma unroll 8
        for (int k = 0; k < KK; ++k) {
            const float s0k = sums[0][k];
            const float s1k = sums[1][k];
            const float w0 = proj_w[k * EE + tid];
            a00 += s0k * w0;
            a01 += s1k * w0;
            if (two) {
                const float w1 = proj_w[k * EE + 512 + tid];
                a10 += s0k * w1;
                a11 += s1k * w1;
            }
        }
        const float pb0 = proj_b[tid];
        const size_t o0 = (size_t)bi0 * EE;
        const size_t o1 = (size_t)(bi0 + 1) * EE;
        out_merge[o0 + tid] = padr[0] ? 0.0f : (a00 + pb0);
        out_merge[o1 + tid] = padr[1] ? 0.0f : (a01 + pb0);
        if (two) {
            const float pb1 = proj_b[512 + tid];
            out_merge[o0 + 512 + tid] = padr[0] ? 0.0f : (a10 + pb1);
            out_merge[o1 + 512 + tid] = padr[1] ? 0.0f : (a11 + pb1);
        }
    }
}

extern "C" void kernel_launch(void* const* d_in, const int* in_sizes, int n_in,
                              void* d_out, int out_size, void* d_ws, size_t ws_size,
                              hipStream_t stream) {
    const float* pos          = (const float*)d_in[0];
    const int* node_type_edge = (const int*)d_in[1];
    const int* padding_mask   = (const int*)d_in[2];
    const int* mask_aa        = (const int*)d_in[3];
    const int* mask_pos       = (const int*)d_in[4];
    const int* time_pos       = (const int*)d_in[5];
    const float* means        = (const float*)d_in[6];
    const float* stds         = (const float*)d_in[7];
    const float* mul_w        = (const float*)d_in[8];
    const float* bias_w       = (const float*)d_in[9];
    const float* proj_w       = (const float*)d_in[10];
    const float* proj_b       = (const float*)d_in[11];
    const float* t_w1         = (const float*)d_in[12];
    const float* t_b1         = (const float*)d_in[13];
    const float* t_w2         = (const float*)d_in[14];
    const float* t_b2         = (const float*)d_in[15];

    float* out       = (float*)d_out;
    float* out_ef    = out;                                        // B*N*N*K
    float* out_merge = out + (size_t)BB * NN * NN * KK;            // B*N*E
    float* out_dp    = out_merge + (size_t)BB * NN * EE;           // B*N*N*3

    edge_fused2r_kernel<<<(BB * NN) / RPB, 512, 0, stream>>>(
        pos, node_type_edge, padding_mask, mask_aa, mask_pos, time_pos,
        means, stds, mul_w, bias_w, proj_w, proj_b,
        t_w1, t_b1, t_w2, t_b2,
        out_ef, out_merge, out_dp);
}

// Round 16
// 59.570 us; speedup vs baseline: 1.4073x; 1.4073x over previous
//
#include <hip/hip_runtime.h>
#include <hip/hip_bf16.h>
#include <math.h>

#define BB 2
#define NN 512
#define KK 128
#define EE 768
#define NUM_EDGES 1536
#define RPB 4   // rows per block; grid = B*N/RPB = 256 blocks x 1024 threads

// ---------------- R14 frame, single change: phase C float2 -> float4 stores ----------------
__global__ __launch_bounds__(1024) void edge_fused4_kernel(
    const float* __restrict__ pos,
    const int* __restrict__ node_type_edge,
    const int* __restrict__ padding_mask,
    const int* __restrict__ mask_aa,
    const int* __restrict__ mask_pos,
    const int* __restrict__ time_pos,
    const float* __restrict__ means,
    const float* __restrict__ stds,
    const float* __restrict__ mul_w,
    const float* __restrict__ bias_w,
    const float* __restrict__ proj_w,   // [K,E]
    const float* __restrict__ proj_b,   // [E]
    const float* __restrict__ t_w1, const float* __restrict__ t_b1,
    const float* __restrict__ t_w2, const float* __restrict__ t_b2,
    float* __restrict__ out_ef,    // [B,N,N,K]
    float* __restrict__ out_merge, // [B,N,E]
    float* __restrict__ out_dp)    // [B,N,N,3]
{
    __shared__ float e2[2][KK];
    __shared__ float h2[2][KK];
    __shared__ float tv[2][KK];            // tv[0]=2*t_enc(t_b), tv[1]=2*t_enc(0)
    __shared__ float xv[RPB][NN];          // per-row mul*dist+bias (8 KB)
    __shared__ unsigned char fl[RPB][NN];  // per-row flags (2 KB)
    __shared__ float red[RPB][8 * KK];     // per-row j-group partials (16 KB)
    __shared__ float sums[RPB][KK];        // per-row k-sums (2 KB)
    __shared__ int padr[RPB];

    const int bi0 = blockIdx.x * RPB;      // 4 rows, same b (512 % 4 == 0)
    const int b = bi0 >> 9;
    const int tid = threadIdx.x;
    const int grp = tid >> 8;              // 0..3 : row group
    const int gt  = tid & 255;             // thread-in-group
    const int bi  = bi0 + grp;
    const int i   = bi & (NN - 1);

    // ---- phase A (threads 0..255, R14-exact) ----
    if (grp == 0) {
        const int enc = gt >> 7;
        const int k = gt & 127;
        const float t = (enc == 0) ? (float)time_pos[b] : 0.0f;
        const int kk = k & 63;
        const float freq = __expf(-logf(10000.0f) * (float)kk * (1.0f / 64.0f));
        const float arg = t * freq;
        e2[enc][k] = (k < 64) ? cosf(arg) : sinf(arg);
    }
    __syncthreads();
    if (grp == 0) {
        const int enc = gt >> 7;
        const int k = gt & 127;
        float acc = t_b1[k];
#pragma unroll 8
        for (int r = 0; r < KK; ++r) acc += e2[enc][r] * t_w1[r * KK + k];
        h2[enc][k] = acc / (1.0f + __expf(-acc));
    }
    __syncthreads();
    if (grp == 0) {
        const int enc = gt >> 7;
        const int k = gt & 127;
        float acc2 = t_b2[k];
#pragma unroll 8
        for (int r = 0; r < KK; ++r) acc2 += h2[enc][r] * t_w2[r * KK + k];
        tv[enc][k] = 2.0f * acc2;
    }

    // ---- phase B: group g handles row g (R14-exact per-thread work) ----
    const float pix = pos[(b * NN + i) * 3 + 0];
    const float piy = pos[(b * NN + i) * 3 + 1];
    const float piz = pos[(b * NN + i) * 3 + 2];
    const int maa_i  = mask_aa[b * NN + i];
    const int mpos_i = mask_pos[b * NN + i];

    for (int j = gt; j < NN; j += 256) {
        const float dx = pos[(b * NN + j) * 3 + 0] - pix;
        const float dy = pos[(b * NN + j) * 3 + 1] - piy;
        const float dz = pos[(b * NN + j) * 3 + 2] - piz;
        const float dist = sqrtf(dx * dx + dy * dy + dz * dz);
        const float invd = 1.0f / (dist + 1e-5f);
        const size_t dpo = ((size_t)bi * NN + j) * 3;
        out_dp[dpo + 0] = dx * invd;
        out_dp[dpo + 1] = dy * invd;
        out_dp[dpo + 2] = dz * invd;

        const int base = (bi * NN + j) * 2;
        int e0 = node_type_edge[base + 0];
        int e1 = node_type_edge[base + 1];
        if (maa_i)               e0 = 0;
        if (mask_aa[b * NN + j]) e1 = 0;
        const float mul  = mul_w[e0]  + mul_w[e1];
        const float bias = bias_w[e0] + bias_w[e1];
        xv[grp][j] = mul * dist + bias;

        const int md  = (mpos_i | mask_pos[b * NN + j]) ? 1 : 0;
        const int pad = padding_mask[b * NN + j] ? 2 : 0;
        fl[grp][j] = (unsigned char)(md | pad);
    }
    if (gt == 0) padr[grp] = padding_mask[b * NN + i];
    __syncthreads();   // tv/xv/fl visible

    // ---- phase C: group g = row g; 4 k/thread, 8 j-groups, float4 stores ----
    const int k0 = (gt & 31) * 4;
    const int jg = gt >> 5;              // 0..7 (wave-uniform halves)
    const float a = sqrtf(2.0f * 3.14159f);

    float mean[4], inv[4], coef[4], t2[4], t02[4];
#pragma unroll
    for (int q = 0; q < 4; ++q) {
        mean[q] = means[k0 + q];
        const float sd = fabsf(stds[k0 + q]) + 0.01f;
        inv[q]  = 1.0f / sd;
        coef[q] = 1.0f / (a * sd);
        t2[q]   = tv[0][k0 + q];
        t02[q]  = tv[1][k0 + q];
    }

    float s[4] = {0.0f, 0.0f, 0.0f, 0.0f};
    const size_t efbase = (size_t)bi * NN * KK;
    const float* __restrict__ xvr = xv[grp];
    const unsigned char* __restrict__ flr = fl[grp];

    for (int jj = 0; jj < NN / 8; ++jj) {
        const int j = jj * 8 + jg;
        const float x = xvr[j];
        const unsigned char f = flr[j];
        float v[4];
#pragma unroll
        for (int q = 0; q < 4; ++q) {
            const float u = (x - mean[q]) * inv[q];
            float val = __expf(-0.5f * u * u) * coef[q] + ((f & 1) ? t2[q] : t02[q]);
            if (f & 2) val = 0.0f;
            s[q] += val;
            v[q] = val;
        }
        float4 st; st.x = v[0]; st.y = v[1]; st.z = v[2]; st.w = v[3];
        *reinterpret_cast<float4*>(&out_ef[efbase + (size_t)j * KK + k0]) = st;
    }

#pragma unroll
    for (int q = 0; q < 4; ++q) red[grp][jg * KK + k0 + q] = s[q];
    __syncthreads();

    // reduce: threads 0..511 -> (row = tid>>7, k = tid&127), 8 groups each
    if (tid < RPB * KK) {
        const int r = tid >> 7;
        const int k = tid & 127;
        const float* rr = red[r];
        float t = 0.0f;
#pragma unroll
        for (int g = 0; g < 8; ++g) t += rr[g * KK + k];
        sums[r][k] = t;
    }
    __syncthreads();

    // ---- phase D: ONE proj_w pass for 4 rows (threads 0..767 own e=tid) ----
    if (tid < EE) {
        const int e = tid;
        float acc0 = 0.f, acc1 = 0.f, acc2 = 0.f, acc3 = 0.f;
#pragma unroll 8
        for (int k = 0; k < KK; ++k) {
            const float w = proj_w[k * EE + e];
            acc0 += sums[0][k] * w;
            acc1 += sums[1][k] * w;
            acc2 += sums[2][k] * w;
            acc3 += sums[3][k] * w;
        }
        const float pb = proj_b[e];
        const size_t o = (size_t)bi0 * EE;
        out_merge[o + e]          = padr[0] ? 0.0f : (acc0 + pb);
        out_merge[o + EE + e]     = padr[1] ? 0.0f : (acc1 + pb);
        out_merge[o + 2 * EE + e] = padr[2] ? 0.0f : (acc2 + pb);
        out_merge[o + 3 * EE + e] = padr[3] ? 0.0f : (acc3 + pb);
    }
}

extern "C" void kernel_launch(void* const* d_in, const int* in_sizes, int n_in,
                              void* d_out, int out_size, void* d_ws, size_t ws_size,
                              hipStream_t stream) {
    const float* pos          = (const float*)d_in[0];
    const int* node_type_edge = (const int*)d_in[1];
    const int* padding_mask   = (const int*)d_in[2];
    const int* mask_aa        = (const int*)d_in[3];
    const int* mask_pos       = (const int*)d_in[4];
    const int* time_pos       = (const int*)d_in[5];
    const float* means        = (const float*)d_in[6];
    const float* stds         = (const float*)d_in[7];
    const float* mul_w        = (const float*)d_in[8];
    const float* bias_w       = (const float*)d_in[9];
    const float* proj_w       = (const float*)d_in[10];
    const float* proj_b       = (const float*)d_in[11];
    const float* t_w1         = (const float*)d_in[12];
    const float* t_b1         = (const float*)d_in[13];
    const float* t_w2         = (const float*)d_in[14];
    const float* t_b2         = (const float*)d_in[15];

    float* out       = (float*)d_out;
    float* out_ef    = out;                                        // B*N*N*K
    float* out_merge = out + (size_t)BB * NN * NN * KK;            // B*N*E
    float* out_dp    = out_merge + (size_t)BB * NN * EE;           // B*N*N*3

    edge_fused4_kernel<<<(BB * NN) / RPB, 1024, 0, stream>>>(
        pos, node_type_edge, padding_mask, mask_aa, mask_pos, time_pos,
        means, stds, mul_w, bias_w, proj_w, proj_b,
        t_w1, t_b1, t_w2, t_b2,
        out_ef, out_merge, out_dp);
}

// Round 17
// 53.790 us; speedup vs baseline: 1.5585x; 1.1074x over previous
//
#include <hip/hip_runtime.h>
#include <hip/hip_bf16.h>
#include <math.h>

#define BB 2
#define NN 512
#define KK 128
#define EE 768
#define NUM_EDGES 1536
#define RPB 4   // rows per block; grid = B*N/RPB = 256 blocks x 1024 threads

// ---------------- R16 frame; changes: A distributed (k-sliced), D vectorized (k-sliced) ----------------
__global__ __launch_bounds__(1024) void edge_fused4_kernel(
    const float* __restrict__ pos,
    const int* __restrict__ node_type_edge,
    const int* __restrict__ padding_mask,
    const int* __restrict__ mask_aa,
    const int* __restrict__ mask_pos,
    const int* __restrict__ time_pos,
    const float* __restrict__ means,
    const float* __restrict__ stds,
    const float* __restrict__ mul_w,
    const float* __restrict__ bias_w,
    const float* __restrict__ proj_w,   // [K,E]
    const float* __restrict__ proj_b,   // [E]
    const float* __restrict__ t_w1, const float* __restrict__ t_b1,
    const float* __restrict__ t_w2, const float* __restrict__ t_b2,
    float* __restrict__ out_ef,    // [B,N,N,K]
    float* __restrict__ out_merge, // [B,N,E]
    float* __restrict__ out_dp)    // [B,N,N,3]
{
    __shared__ float e2[2][KK];
    __shared__ float h2[2][KK];
    __shared__ float tv[2][KK];            // tv[0]=2*t_enc(t_b), tv[1]=2*t_enc(0)
    __shared__ float red_a[4][2][KK];      // A-layer k-slice partials (4 KB)
    __shared__ float xv[RPB][NN];          // per-row mul*dist+bias (8 KB)
    __shared__ unsigned char fl[RPB][NN];  // per-row flags (2 KB)
    __shared__ float red[RPB][8 * KK];     // per-row j-group partials (16 KB)
    __shared__ float sums[RPB][KK];        // per-row k-sums (2 KB)
    __shared__ float4 f4red[4][RPB][192];  // D k-slice partials (48 KB)
    __shared__ int padr[RPB];

    const int bi0 = blockIdx.x * RPB;      // 4 rows, same b (512 % 4 == 0)
    const int b = bi0 >> 9;
    const int tid = threadIdx.x;
    const int grp = tid >> 8;              // 0..3 : row group / k-slice
    const int gt  = tid & 255;             // thread-in-group
    const int bi  = bi0 + grp;
    const int i   = bi & (NN - 1);
    const int enc = gt >> 7;               // 0..1 (A usage)
    const int ak  = gt & 127;              // k within A

    // ---- stage A0 (grp0): sinusoidal embedding ----
    if (grp == 0) {
        const float t = (enc == 0) ? (float)time_pos[b] : 0.0f;
        const int kk = ak & 63;
        const float freq = __expf(-logf(10000.0f) * (float)kk * (1.0f / 64.0f));
        const float arg = t * freq;
        e2[enc][ak] = (ak < 64) ? cosf(arg) : sinf(arg);
    }
    __syncthreads();

    // ---- stage A1 (all 1024): layer-1 partials over 32-term k-slice ----
    {
        const int r0 = grp * 32;
        float p = 0.0f;
#pragma unroll 8
        for (int r = 0; r < 32; ++r) p += e2[enc][r0 + r] * t_w1[(r0 + r) * KK + ak];
        red_a[grp][enc][ak] = p;
    }
    __syncthreads();

    // ---- stage A2 (grp0): reduce + bias + SiLU ----
    if (grp == 0) {
        float acc = t_b1[ak] + red_a[0][enc][ak] + red_a[1][enc][ak]
                             + red_a[2][enc][ak] + red_a[3][enc][ak];
        h2[enc][ak] = acc / (1.0f + __expf(-acc));
    }
    __syncthreads();

    // ---- stage A3 (all 1024): layer-2 partials ----
    {
        const int r0 = grp * 32;
        float p = 0.0f;
#pragma unroll 8
        for (int r = 0; r < 32; ++r) p += h2[enc][r0 + r] * t_w2[(r0 + r) * KK + ak];
        red_a[grp][enc][ak] = p;
    }
    __syncthreads();

    // ---- stage A4 (grp0): tv; then everyone does phase B ----
    if (grp == 0) {
        tv[enc][ak] = 2.0f * (t_b2[ak] + red_a[0][enc][ak] + red_a[1][enc][ak]
                                       + red_a[2][enc][ak] + red_a[3][enc][ak]);
    }

    // ---- phase B: group g handles row g (R16-exact) ----
    const float pix = pos[(b * NN + i) * 3 + 0];
    const float piy = pos[(b * NN + i) * 3 + 1];
    const float piz = pos[(b * NN + i) * 3 + 2];
    const int maa_i  = mask_aa[b * NN + i];
    const int mpos_i = mask_pos[b * NN + i];

    for (int j = gt; j < NN; j += 256) {
        const float dx = pos[(b * NN + j) * 3 + 0] - pix;
        const float dy = pos[(b * NN + j) * 3 + 1] - piy;
        const float dz = pos[(b * NN + j) * 3 + 2] - piz;
        const float dist = sqrtf(dx * dx + dy * dy + dz * dz);
        const float invd = 1.0f / (dist + 1e-5f);
        const size_t dpo = ((size_t)bi * NN + j) * 3;
        out_dp[dpo + 0] = dx * invd;
        out_dp[dpo + 1] = dy * invd;
        out_dp[dpo + 2] = dz * invd;

        const int base = (bi * NN + j) * 2;
        int e0 = node_type_edge[base + 0];
        int e1 = node_type_edge[base + 1];
        if (maa_i)               e0 = 0;
        if (mask_aa[b * NN + j]) e1 = 0;
        const float mul  = mul_w[e0]  + mul_w[e1];
        const float bias = bias_w[e0] + bias_w[e1];
        xv[grp][j] = mul * dist + bias;

        const int md  = (mpos_i | mask_pos[b * NN + j]) ? 1 : 0;
        const int pad = padding_mask[b * NN + j] ? 2 : 0;
        fl[grp][j] = (unsigned char)(md | pad);
    }
    if (gt == 0) padr[grp] = padding_mask[b * NN + i];
    __syncthreads();   // tv/xv/fl visible

    // ---- phase C: group g = row g; 4 k/thread, 8 j-groups, float4 stores (R16-exact) ----
    const int k0 = (gt & 31) * 4;
    const int jg = gt >> 5;              // 0..7
    const float a = sqrtf(2.0f * 3.14159f);

    float mean[4], inv[4], coef[4], t2[4], t02[4];
#pragma unroll
    for (int q = 0; q < 4; ++q) {
        mean[q] = means[k0 + q];
        const float sd = fabsf(stds[k0 + q]) + 0.01f;
        inv[q]  = 1.0f / sd;
        coef[q] = 1.0f / (a * sd);
        t2[q]   = tv[0][k0 + q];
        t02[q]  = tv[1][k0 + q];
    }

    float s[4] = {0.0f, 0.0f, 0.0f, 0.0f};
    const size_t efbase = (size_t)bi * NN * KK;
    const float* __restrict__ xvr = xv[grp];
    const unsigned char* __restrict__ flr = fl[grp];

    for (int jj = 0; jj < NN / 8; ++jj) {
        const int j = jj * 8 + jg;
        const float x = xvr[j];
        const unsigned char f = flr[j];
        float v[4];
#pragma unroll
        for (int q = 0; q < 4; ++q) {
            const float u = (x - mean[q]) * inv[q];
            float val = __expf(-0.5f * u * u) * coef[q] + ((f & 1) ? t2[q] : t02[q]);
            if (f & 2) val = 0.0f;
            s[q] += val;
            v[q] = val;
        }
        float4 st; st.x = v[0]; st.y = v[1]; st.z = v[2]; st.w = v[3];
        *reinterpret_cast<float4*>(&out_ef[efbase + (size_t)j * KK + k0]) = st;
    }

#pragma unroll
    for (int q = 0; q < 4; ++q) red[grp][jg * KK + k0 + q] = s[q];
    __syncthreads();

    // reduce: threads 0..511 -> (row = tid>>7, k = tid&127), 8 groups each
    if (tid < RPB * KK) {
        const int r = tid >> 7;
        const int k = tid & 127;
        const float* rr = red[r];
        float t = 0.0f;
#pragma unroll
        for (int g = 0; g < 8; ++g) t += rr[g * KK + k];
        sums[r][k] = t;
    }
    __syncthreads();

    // ---- phase D: k-sliced, float4 W loads; threads 0..767 ----
    if (tid < 768) {
        const int s4 = tid / 192;          // k-slice 0..3 (wave-aligned: 192 = 3 waves)
        const int e4 = tid % 192;
        const int e0 = e4 * 4;
        float4 acc[RPB];
#pragma unroll
        for (int r = 0; r < RPB; ++r) { acc[r].x = 0.f; acc[r].y = 0.f; acc[r].z = 0.f; acc[r].w = 0.f; }
        const int kbeg = s4 * 32;
#pragma unroll 8
        for (int kk2 = 0; kk2 < 32; ++kk2) {
            const int k = kbeg + kk2;
            const float4 w = *reinterpret_cast<const float4*>(&proj_w[k * EE + e0]);
#pragma unroll
            for (int r = 0; r < RPB; ++r) {
                const float sv = sums[r][k];
                acc[r].x += sv * w.x;
                acc[r].y += sv * w.y;
                acc[r].z += sv * w.z;
                acc[r].w += sv * w.w;
            }
        }
#pragma unroll
        for (int r = 0; r < RPB; ++r) f4red[s4][r][e4] = acc[r];
    }
    __syncthreads();

    if (tid < 768) {
        const int r  = tid / 192;
        const int e4 = tid % 192;
        const int e0 = e4 * 4;
        const float4 p0 = f4red[0][r][e4];
        const float4 p1 = f4red[1][r][e4];
        const float4 p2 = f4red[2][r][e4];
        const float4 p3 = f4red[3][r][e4];
        const float4 pb = *reinterpret_cast<const float4*>(&proj_b[e0]);
        const bool p = padr[r] != 0;
        float4 o;
        o.x = p ? 0.f : (p0.x + p1.x + p2.x + p3.x + pb.x);
        o.y = p ? 0.f : (p0.y + p1.y + p2.y + p3.y + pb.y);
        o.z = p ? 0.f : (p0.z + p1.z + p2.z + p3.z + pb.z);
        o.w = p ? 0.f : (p0.w + p1.w + p2.w + p3.w + pb.w);
        *reinterpret_cast<float4*>(&out_merge[(size_t)(bi0 + r) * EE + e0]) = o;
    }
}

extern "C" void kernel_launch(void* const* d_in, const int* in_sizes, int n_in,
                              void* d_out, int out_size, void* d_ws, size_t ws_size,
                              hipStream_t stream) {
    const float* pos          = (const float*)d_in[0];
    const int* node_type_edge = (const int*)d_in[1];
    const int* padding_mask   = (const int*)d_in[2];
    const int* mask_aa        = (const int*)d_in[3];
    const int* mask_pos       = (const int*)d_in[4];
    const int* time_pos       = (const int*)d_in[5];
    const float* means        = (const float*)d_in[6];
    const float* stds         = (const float*)d_in[7];
    const float* mul_w        = (const float*)d_in[8];
    const float* bias_w       = (const float*)d_in[9];
    const float* proj_w       = (const float*)d_in[10];
    const float* proj_b       = (const float*)d_in[11];
    const float* t_w1         = (const float*)d_in[12];
    const float* t_b1         = (const float*)d_in[13];
    const float* t_w2         = (const float*)d_in[14];
    const float* t_b2         = (const float*)d_in[15];

    float* out       = (float*)d_out;
    float* out_ef    = out;                                        // B*N*N*K
    float* out_merge = out + (size_t)BB * NN * NN * KK;            // B*N*E
    float* out_dp    = out_merge + (size_t)BB * NN * EE;           // B*N*N*3

    edge_fused4_kernel<<<(BB * NN) / RPB, 1024, 0, stream>>>(
        pos, node_type_edge, padding_mask, mask_aa, mask_pos, time_pos,
        means, stds, mul_w, bias_w, proj_w, proj_b,
        t_w1, t_b1, t_w2, t_b2,
        out_ef, out_merge, out_dp);
}

// Round 18
// 53.084 us; speedup vs baseline: 1.5792x; 1.0133x over previous
//
#include <hip/hip_runtime.h>
#include <hip/hip_bf16.h>
#include <math.h>

#define BB 2
#define NN 512
#define KK 128
#define EE 768
#define NUM_EDGES 1536
#define RPB 4   // rows per block; grid = B*N/RPB = 256 blocks x 1024 threads

// ---------------- R17 frame; single change: B-loads prefetched into registers
// before the A barrier chain (load latency hides under A's compute+drains) ----
__global__ __launch_bounds__(1024) void edge_fused4_kernel(
    const float* __restrict__ pos,
    const int* __restrict__ node_type_edge,
    const int* __restrict__ padding_mask,
    const int* __restrict__ mask_aa,
    const int* __restrict__ mask_pos,
    const int* __restrict__ time_pos,
    const float* __restrict__ means,
    const float* __restrict__ stds,
    const float* __restrict__ mul_w,
    const float* __restrict__ bias_w,
    const float* __restrict__ proj_w,   // [K,E]
    const float* __restrict__ proj_b,   // [E]
    const float* __restrict__ t_w1, const float* __restrict__ t_b1,
    const float* __restrict__ t_w2, const float* __restrict__ t_b2,
    float* __restrict__ out_ef,    // [B,N,N,K]
    float* __restrict__ out_merge, // [B,N,E]
    float* __restrict__ out_dp)    // [B,N,N,3]
{
    __shared__ float e2[2][KK];
    __shared__ float h2[2][KK];
    __shared__ float tv[2][KK];            // tv[0]=2*t_enc(t_b), tv[1]=2*t_enc(0)
    __shared__ float red_a[4][2][KK];      // A-layer k-slice partials (4 KB)
    __shared__ float xv[RPB][NN];          // per-row mul*dist+bias (8 KB)
    __shared__ unsigned char fl[RPB][NN];  // per-row flags (2 KB)
    __shared__ float red[RPB][8 * KK];     // per-row j-group partials (16 KB)
    __shared__ float sums[RPB][KK];        // per-row k-sums (2 KB)
    __shared__ float4 f4red[4][RPB][192];  // D k-slice partials (48 KB)
    __shared__ int padr[RPB];

    const int bi0 = blockIdx.x * RPB;      // 4 rows, same b (512 % 4 == 0)
    const int b = bi0 >> 9;
    const int tid = threadIdx.x;
    const int grp = tid >> 8;              // 0..3 : row group / k-slice
    const int gt  = tid & 255;             // thread-in-group
    const int bi  = bi0 + grp;
    const int i   = bi & (NN - 1);
    const int enc = gt >> 7;               // 0..1 (A usage)
    const int ak  = gt & 127;              // k within A

    // ---- B prefetch: issue ALL phase-B global loads into registers NOW.
    //      The A-barrier vmcnt(0) drains cover their latency. ----
    const int j0 = gt, j1 = gt + 256;
    const float pix = pos[(b * NN + i) * 3 + 0];
    const float piy = pos[(b * NN + i) * 3 + 1];
    const float piz = pos[(b * NN + i) * 3 + 2];
    const int maa_i  = mask_aa[b * NN + i];
    const int mpos_i = mask_pos[b * NN + i];

    const float p0x = pos[(b * NN + j0) * 3 + 0];
    const float p0y = pos[(b * NN + j0) * 3 + 1];
    const float p0z = pos[(b * NN + j0) * 3 + 2];
    const float p1x = pos[(b * NN + j1) * 3 + 0];
    const float p1y = pos[(b * NN + j1) * 3 + 1];
    const float p1z = pos[(b * NN + j1) * 3 + 2];
    int e00 = node_type_edge[(bi * NN + j0) * 2 + 0];
    int e01 = node_type_edge[(bi * NN + j0) * 2 + 1];
    int e10 = node_type_edge[(bi * NN + j1) * 2 + 0];
    int e11 = node_type_edge[(bi * NN + j1) * 2 + 1];
    const int maa_j0 = mask_aa[b * NN + j0];
    const int maa_j1 = mask_aa[b * NN + j1];
    const int mp_j0  = mask_pos[b * NN + j0];
    const int mp_j1  = mask_pos[b * NN + j1];
    const int pd_j0  = padding_mask[b * NN + j0];
    const int pd_j1  = padding_mask[b * NN + j1];
    if (gt == 0) padr[grp] = padding_mask[b * NN + i];

    // ---- stage A0 (grp0): sinusoidal embedding ----
    if (grp == 0) {
        const float t = (enc == 0) ? (float)time_pos[b] : 0.0f;
        const int kk = ak & 63;
        const float freq = __expf(-logf(10000.0f) * (float)kk * (1.0f / 64.0f));
        const float arg = t * freq;
        e2[enc][ak] = (ak < 64) ? cosf(arg) : sinf(arg);
    }
    __syncthreads();

    // ---- stage A1 (all 1024): layer-1 partials over 32-term k-slice ----
    {
        const int r0 = grp * 32;
        float p = 0.0f;
#pragma unroll 8
        for (int r = 0; r < 32; ++r) p += e2[enc][r0 + r] * t_w1[(r0 + r) * KK + ak];
        red_a[grp][enc][ak] = p;
    }
    __syncthreads();

    // ---- stage A2 (grp0): reduce + bias + SiLU ----
    if (grp == 0) {
        float acc = t_b1[ak] + red_a[0][enc][ak] + red_a[1][enc][ak]
                             + red_a[2][enc][ak] + red_a[3][enc][ak];
        h2[enc][ak] = acc / (1.0f + __expf(-acc));
    }
    __syncthreads();

    // ---- stage A3 (all 1024): layer-2 partials ----
    {
        const int r0 = grp * 32;
        float p = 0.0f;
#pragma unroll 8
        for (int r = 0; r < 32; ++r) p += h2[enc][r0 + r] * t_w2[(r0 + r) * KK + ak];
        red_a[grp][enc][ak] = p;
    }
    __syncthreads();

    // ---- stage A4 (grp0): tv ----
    if (grp == 0) {
        tv[enc][ak] = 2.0f * (t_b2[ak] + red_a[0][enc][ak] + red_a[1][enc][ak]
                                       + red_a[2][enc][ak] + red_a[3][enc][ak]);
    }

    // ---- phase B compute: pure VALU from prefetched registers ----
    {
        // j0
        {
            const float dx = p0x - pix, dy = p0y - piy, dz = p0z - piz;
            const float dist = sqrtf(dx * dx + dy * dy + dz * dz);
            const float invd = 1.0f / (dist + 1e-5f);
            const size_t dpo = ((size_t)bi * NN + j0) * 3;
            out_dp[dpo + 0] = dx * invd;
            out_dp[dpo + 1] = dy * invd;
            out_dp[dpo + 2] = dz * invd;
            int e0 = maa_i ? 0 : e00;
            int e1 = maa_j0 ? 0 : e01;
            xv[grp][j0] = (mul_w[e0] + mul_w[e1]) * dist + (bias_w[e0] + bias_w[e1]);
            fl[grp][j0] = (unsigned char)(((mpos_i | mp_j0) ? 1 : 0) | (pd_j0 ? 2 : 0));
        }
        // j1
        {
            const float dx = p1x - pix, dy = p1y - piy, dz = p1z - piz;
            const float dist = sqrtf(dx * dx + dy * dy + dz * dz);
            const float invd = 1.0f / (dist + 1e-5f);
            const size_t dpo = ((size_t)bi * NN + j1) * 3;
            out_dp[dpo + 0] = dx * invd;
            out_dp[dpo + 1] = dy * invd;
            out_dp[dpo + 2] = dz * invd;
            int e0 = maa_i ? 0 : e10;
            int e1 = maa_j1 ? 0 : e11;
            xv[grp][j1] = (mul_w[e0] + mul_w[e1]) * dist + (bias_w[e0] + bias_w[e1]);
            fl[grp][j1] = (unsigned char)(((mpos_i | mp_j1) ? 1 : 0) | (pd_j1 ? 2 : 0));
        }
    }
    __syncthreads();   // tv/xv/fl visible

    // ---- phase C: group g = row g; 4 k/thread, 8 j-groups, float4 stores (R17-exact) ----
    const int k0 = (gt & 31) * 4;
    const int jg = gt >> 5;              // 0..7
    const float a = sqrtf(2.0f * 3.14159f);

    float mean[4], inv[4], coef[4], t2[4], t02[4];
#pragma unroll
    for (int q = 0; q < 4; ++q) {
        mean[q] = means[k0 + q];
        const float sd = fabsf(stds[k0 + q]) + 0.01f;
        inv[q]  = 1.0f / sd;
        coef[q] = 1.0f / (a * sd);
        t2[q]   = tv[0][k0 + q];
        t02[q]  = tv[1][k0 + q];
    }

    float s[4] = {0.0f, 0.0f, 0.0f, 0.0f};
    const size_t efbase = (size_t)bi * NN * KK;
    const float* __restrict__ xvr = xv[grp];
    const unsigned char* __restrict__ flr = fl[grp];

    for (int jj = 0; jj < NN / 8; ++jj) {
        const int j = jj * 8 + jg;
        const float x = xvr[j];
        const unsigned char f = flr[j];
        float v[4];
#pragma unroll
        for (int q = 0; q < 4; ++q) {
            const float u = (x - mean[q]) * inv[q];
            float val = __expf(-0.5f * u * u) * coef[q] + ((f & 1) ? t2[q] : t02[q]);
            if (f & 2) val = 0.0f;
            s[q] += val;
            v[q] = val;
        }
        float4 st; st.x = v[0]; st.y = v[1]; st.z = v[2]; st.w = v[3];
        *reinterpret_cast<float4*>(&out_ef[efbase + (size_t)j * KK + k0]) = st;
    }

#pragma unroll
    for (int q = 0; q < 4; ++q) red[grp][jg * KK + k0 + q] = s[q];
    __syncthreads();

    // reduce: threads 0..511 -> (row = tid>>7, k = tid&127), 8 groups each
    if (tid < RPB * KK) {
        const int r = tid >> 7;
        const int k = tid & 127;
        const float* rr = red[r];
        float t = 0.0f;
#pragma unroll
        for (int g = 0; g < 8; ++g) t += rr[g * KK + k];
        sums[r][k] = t;
    }
    __syncthreads();

    // ---- phase D: k-sliced, float4 W loads; threads 0..767 (R17-exact) ----
    if (tid < 768) {
        const int s4 = tid / 192;          // k-slice 0..3
        const int e4 = tid % 192;
        const int e0 = e4 * 4;
        float4 acc[RPB];
#pragma unroll
        for (int r = 0; r < RPB; ++r) { acc[r].x = 0.f; acc[r].y = 0.f; acc[r].z = 0.f; acc[r].w = 0.f; }
        const int kbeg = s4 * 32;
#pragma unroll 8
        for (int kk2 = 0; kk2 < 32; ++kk2) {
            const int k = kbeg + kk2;
            const float4 w = *reinterpret_cast<const float4*>(&proj_w[k * EE + e0]);
#pragma unroll
            for (int r = 0; r < RPB; ++r) {
                const float sv = sums[r][k];
                acc[r].x += sv * w.x;
                acc[r].y += sv * w.y;
                acc[r].z += sv * w.z;
                acc[r].w += sv * w.w;
            }
        }
#pragma unroll
        for (int r = 0; r < RPB; ++r) f4red[s4][r][e4] = acc[r];
    }
    __syncthreads();

    if (tid < 768) {
        const int r  = tid / 192;
        const int e4 = tid % 192;
        const int e0 = e4 * 4;
        const float4 p0 = f4red[0][r][e4];
        const float4 p1 = f4red[1][r][e4];
        const float4 p2 = f4red[2][r][e4];
        const float4 p3 = f4red[3][r][e4];
        const float4 pb = *reinterpret_cast<const float4*>(&proj_b[e0]);
        const bool p = padr[r] != 0;
        float4 o;
        o.x = p ? 0.f : (p0.x + p1.x + p2.x + p3.x + pb.x);
        o.y = p ? 0.f : (p0.y + p1.y + p2.y + p3.y + pb.y);
        o.z = p ? 0.f : (p0.z + p1.z + p2.z + p3.z + pb.z);
        o.w = p ? 0.f : (p0.w + p1.w + p2.w + p3.w + pb.w);
        *reinterpret_cast<float4*>(&out_merge[(size_t)(bi0 + r) * EE + e0]) = o;
    }
}

extern "C" void kernel_launch(void* const* d_in, const int* in_sizes, int n_in,
                              void* d_out, int out_size, void* d_ws, size_t ws_size,
                              hipStream_t stream) {
    const float* pos          = (const float*)d_in[0];
    const int* node_type_edge = (const int*)d_in[1];
    const int* padding_mask   = (const int*)d_in[2];
    const int* mask_aa        = (const int*)d_in[3];
    const int* mask_pos       = (const int*)d_in[4];
    const int* time_pos       = (const int*)d_in[5];
    const float* means        = (const float*)d_in[6];
    const float* stds         = (const float*)d_in[7];
    const float* mul_w        = (const float*)d_in[8];
    const float* bias_w       = (const float*)d_in[9];
    const float* proj_w       = (const float*)d_in[10];
    const float* proj_b       = (const float*)d_in[11];
    const float* t_w1         = (const float*)d_in[12];
    const float* t_b1         = (const float*)d_in[13];
    const float* t_w2         = (const float*)d_in[14];
    const float* t_b2         = (const float*)d_in[15];

    float* out       = (float*)d_out;
    float* out_ef    = out;                                        // B*N*N*K
    float* out_merge = out + (size_t)BB * NN * NN * KK;            // B*N*E
    float* out_dp    = out_merge + (size_t)BB * NN * EE;           // B*N*N*3

    edge_fused4_kernel<<<(BB * NN) / RPB, 1024, 0, stream>>>(
        pos, node_type_edge, padding_mask, mask_aa, mask_pos, time_pos,
        means, stds, mul_w, bias_w, proj_w, proj_b,
        t_w1, t_b1, t_w2, t_b2,
        out_ef, out_merge, out_dp);
}